// Round 9
// baseline (174.704 us; speedup 1.0000x reference)
//
#include <hip/hip_runtime.h>
#include <stdint.h>

#define NTOK 16384
#define KVB 64

typedef __attribute__((ext_vector_type(8))) short short8;
typedef __attribute__((ext_vector_type(4))) float f32x4;
typedef __attribute__((ext_vector_type(16))) float f32x16;

// round-to-nearest-even f32 -> bf16 (bit pattern as short)
__device__ __forceinline__ short f2bf_rne(float f) {
  union { float f; unsigned u; } a; a.f = f;
  unsigned r = a.u + 0x7fffu + ((a.u >> 16) & 1u);
  return (short)(r >> 16);
}

// compiler-managed v_exp_f32 (raw asm bypasses the trans-op hazard recognizer)
__device__ __forceinline__ float fast_exp2(float x) {
#if __has_builtin(__builtin_amdgcn_exp2f)
  return __builtin_amdgcn_exp2f(x);
#else
  return exp2f(x);
#endif
}

__device__ __forceinline__ unsigned cvt_pk_bf16(float lo, float hi) {
  unsigned r;
  asm("v_cvt_pk_bf16_f32 %0, %1, %2" : "=v"(r) : "v"(lo), "v"(hi));
  return r;
}

// sigma: involution on 0..31 swapping [4-7]<->[8-11] and [20-23]<->[24-27].
// Storing K row k at slot sigma(k) makes the 32x32 QK^T output's C-rows land
// so that exp'd P packs sequentially into the PV A-fragment (no cross-lane).
__device__ __forceinline__ int sigma32(int s) {
  int t = (s >> 2) & 3;
  return (t == 1 || t == 2) ? (s ^ 12) : s;
}

// ---------------- projection: Q and K in one pass ([N][8] bf16 rows) ----
// K pre-scaled by 1/ln2 (v_exp_f32 = 2^x) and stored sigma-permuted.
__global__ __launch_bounds__(256) void proj_qk_kernel(
    const float* __restrict__ x,
    const float* __restrict__ Wq, const float* __restrict__ bq,
    const float* __restrict__ Wk, const float* __restrict__ bk,
    short* __restrict__ Qp, short* __restrict__ Kp)
{
  __shared__ float sWq[512], sWk[512], sbq[8], sbk[8];
  const int tid = threadIdx.x;
  for (int i = tid; i < 512; i += 256) { sWq[i] = Wq[i]; sWk[i] = Wk[i]; }
  if (tid < 8) { sbq[tid] = bq[tid]; sbk[tid] = bk[tid]; }
  __syncthreads();

  const int n = blockIdx.x * 256 + tid;
  float xv[64];
#pragma unroll
  for (int c = 0; c < 64; ++c) xv[c] = x[c * NTOK + n];

  short8 qv, kv;
#pragma unroll
  for (int d = 0; d < 8; ++d) {
    float qa = sbq[d], ka = sbk[d];
#pragma unroll
    for (int c = 0; c < 64; c += 4) {
      f32x4 wq = *reinterpret_cast<const f32x4*>(&sWq[d * 64 + c]);
      f32x4 wk = *reinterpret_cast<const f32x4*>(&sWk[d * 64 + c]);
      qa += wq[0]*xv[c] + wq[1]*xv[c+1] + wq[2]*xv[c+2] + wq[3]*xv[c+3];
      ka += wk[0]*xv[c] + wk[1]*xv[c+1] + wk[2]*xv[c+2] + wk[3]*xv[c+3];
    }
    qv[d] = f2bf_rne(qa);
    kv[d] = f2bf_rne(ka * 1.44269504f);
  }
  *reinterpret_cast<short8*>(Qp + (size_t)n * 8) = qv;
  const int slot = (n & ~31) | sigma32(n & 31);
  *reinterpret_cast<short8*>(Kp + (size_t)slot * 8) = kv;
}

// ---------------- projection: plain V^T (no permutation needed) ---------
__global__ __launch_bounds__(256) void proj_v_kernel(
    const float* __restrict__ x,
    const float* __restrict__ Wv, const float* __restrict__ bv,
    short* __restrict__ Vp)
{
  __shared__ float sW[4096];
  __shared__ float sb[64];
  const int tid = threadIdx.x;
  for (int i = tid; i < 4096; i += 256) sW[i] = Wv[i];
  if (tid < 64) sb[tid] = bv[tid];
  __syncthreads();

  const int n = blockIdx.x * 256 + tid;
  float xv[64];
#pragma unroll
  for (int c = 0; c < 64; ++c) xv[c] = x[c * NTOK + n];

#pragma unroll
  for (int d = 0; d < 64; ++d) {
    float a = sb[d];
#pragma unroll
    for (int c = 0; c < 64; c += 4) {
      f32x4 wv = *reinterpret_cast<const f32x4*>(&sW[d * 64 + c]);
      a += wv[0]*xv[c] + wv[1]*xv[c+1] + wv[2]*xv[c+2] + wv[3]*xv[c+3];
    }
    Vp[(size_t)d * NTOK + n] = f2bf_rne(a);
  }
}

// ---------------- fused attention: 32x32x16 MFMA, split-K, no LDS -------
// Wave owns 32 q-rows. Swapped QK^T (A=K sigma-permuted, B=Q zero-padded
// d8->16). Lane (q=lane&31,hi) gets S for its q at 16 keys; exp'd P packs
// sequentially into PV A-frags (sigma absorbed the layout). lsum is a pure
// per-lane add chain + one shfl_xor(32) at the end. Partials additive.
__global__ __launch_bounds__(256, 4) void attn_split_kernel(
    const short* __restrict__ Qp, const short* __restrict__ Kp,
    const short* __restrict__ Vp,
    float* __restrict__ part, float* __restrict__ lsums, int splits)
{
  const int tid  = threadIdx.x;
  const int w    = tid >> 6;
  const int lane = tid & 63;
  const int hi   = lane >> 5;
  const int ln   = lane & 31;
  const int s    = blockIdx.x;
  const int qw   = blockIdx.y * 4 + w;   // 0..511
  const int q0   = qw * 32;

  const short8 zero8 = {0,0,0,0,0,0,0,0};
  f32x16 zf16;
#pragma unroll
  for (int i = 0; i < 16; ++i) zf16[i] = 0.f;

  // Q fragment: B[k=8hi+e][q=ln]; hi half zero (d=8 padded to K=16)
  short8 qf = hi ? zero8
                 : *reinterpret_cast<const short8*>(Qp + (size_t)(q0 + ln) * 8);

  f32x16 acc0 = zf16, acc1 = zf16;   // c 0-31 / c 32-63
  float lsum = 0.f;

  const int kvlen = NTOK / splits;
  const int kv_lo = s * kvlen;

  // A rows: all lanes load real K rows (hi lanes' A[k>=8] is killed by B=0)
  const short* kp = Kp + ((size_t)kv_lo + ln) * 8;
  const short* va = Vp + (size_t)ln * NTOK + kv_lo + 8 * hi;         // c 0-31
  const short* vb = Vp + (size_t)(32 + ln) * NTOK + kv_lo + 8 * hi;  // c 32-63

#pragma unroll 2
  for (int it = 0; it < kvlen; it += KVB) {
    short8 kf0 = *reinterpret_cast<const short8*>(kp);
    short8 kf1 = *reinterpret_cast<const short8*>(kp + 32 * 8);
    f32x16 sv0 = __builtin_amdgcn_mfma_f32_32x32x16_bf16(kf0, qf, zf16, 0, 0, 0);
    f32x16 sv1 = __builtin_amdgcn_mfma_f32_32x32x16_bf16(kf1, qf, zf16, 0, 0, 0);

#pragma unroll
    for (int b = 0; b < 2; ++b) {
      const f32x16& sv = b ? sv1 : sv0;
      const int off = 32 * b;
      float e[16];
#pragma unroll
      for (int r = 0; r < 16; ++r) e[r] = fast_exp2(sv[r]);
#pragma unroll
      for (int r = 0; r < 16; ++r) lsum += e[r];

      union { short8 s8; unsigned u32[4]; } pa0, pa1;
      pa0.u32[0] = cvt_pk_bf16(e[0],  e[1]);
      pa0.u32[1] = cvt_pk_bf16(e[2],  e[3]);
      pa0.u32[2] = cvt_pk_bf16(e[4],  e[5]);
      pa0.u32[3] = cvt_pk_bf16(e[6],  e[7]);
      pa1.u32[0] = cvt_pk_bf16(e[8],  e[9]);
      pa1.u32[1] = cvt_pk_bf16(e[10], e[11]);
      pa1.u32[2] = cvt_pk_bf16(e[12], e[13]);
      pa1.u32[3] = cvt_pk_bf16(e[14], e[15]);

      short8 vf0a = *reinterpret_cast<const short8*>(va + off);
      short8 vf0b = *reinterpret_cast<const short8*>(vb + off);
      acc0 = __builtin_amdgcn_mfma_f32_32x32x16_bf16(pa0.s8, vf0a, acc0, 0, 0, 0);
      acc1 = __builtin_amdgcn_mfma_f32_32x32x16_bf16(pa0.s8, vf0b, acc1, 0, 0, 0);
      short8 vf1a = *reinterpret_cast<const short8*>(va + off + 16);
      short8 vf1b = *reinterpret_cast<const short8*>(vb + off + 16);
      acc0 = __builtin_amdgcn_mfma_f32_32x32x16_bf16(pa1.s8, vf1a, acc0, 0, 0, 0);
      acc1 = __builtin_amdgcn_mfma_f32_32x32x16_bf16(pa1.s8, vf1b, acc1, 0, 0, 0);
    }
    kp += KVB * 8;
    va += KVB; vb += KVB;
  }

  // full row denominator for q = ln (hi halves cover disjoint key sets)
  lsum += __shfl_xor(lsum, 32);
  if (lane < 32)
    lsums[(size_t)s * NTOK + q0 + ln] = lsum;

  // partial O, q-major [q][64c]; C layout: row=(r&3)+8*(r>>2)+4*hi, col=ln
  float* pp = part + ((size_t)s * NTOK + q0) * 64;
#pragma unroll
  for (int r = 0; r < 16; ++r) {
    const int qrow = (r & 3) + 8 * (r >> 2) + 4 * hi;
    pp[qrow * 64 + ln]      = acc0[r];
    pp[qrow * 64 + 32 + ln] = acc1[r];
  }
}

// ---------------- reduce: sum partials, normalize, gamma*O + x ----------
__global__ __launch_bounds__(256) void reduce_kernel(
    const float* __restrict__ part, const float* __restrict__ lsums,
    const float* __restrict__ x, const float* __restrict__ gamma,
    float* __restrict__ out, int splits)
{
  __shared__ float tile[64][65];
  __shared__ float linv[64];
  const int tid = threadIdx.x;
  const int qb  = blockIdx.x;

  // phase 1: coalesced q-major reads, sum over splits
  {
    const int qloc = tid >> 2, c0 = (tid & 3) * 16;
    f32x4 a[4] = {{0,0,0,0},{0,0,0,0},{0,0,0,0},{0,0,0,0}};
    float ls = 0.f;
    for (int s = 0; s < splits; ++s) {
      const float* p = part + ((size_t)s * NTOK + qb * 64 + qloc) * 64 + c0;
#pragma unroll
      for (int j = 0; j < 4; ++j)
        a[j] += *reinterpret_cast<const f32x4*>(p + 4 * j);
      if ((tid & 3) == 0)
        ls += lsums[(size_t)s * NTOK + qb * 64 + qloc];
    }
#pragma unroll
    for (int j = 0; j < 4; ++j)
#pragma unroll
      for (int e = 0; e < 4; ++e)
        tile[qloc][c0 + 4 * j + e] = a[j][e];
    if ((tid & 3) == 0) linv[qloc] = 1.f / ls;
  }
  __syncthreads();

  // phase 2: c-major writes (transposed via LDS)
  const int c = tid >> 2, qs = (tid & 3) * 16;
  const float gam = gamma[0];
#pragma unroll
  for (int i = 0; i < 16; ++i) {
    const int q = qs + i;
    const size_t idx = (size_t)c * NTOK + qb * 64 + q;
    out[idx] = gam * tile[q][c] * linv[q] + x[idx];
  }
}

extern "C" void kernel_launch(void* const* d_in, const int* in_sizes, int n_in,
                              void* d_out, int out_size, void* d_ws, size_t ws_size,
                              hipStream_t stream) {
  const float* x     = (const float*)d_in[0];
  const float* Wq    = (const float*)d_in[1];
  const float* bq    = (const float*)d_in[2];
  const float* Wk    = (const float*)d_in[3];
  const float* bk    = (const float*)d_in[4];
  const float* Wv    = (const float*)d_in[5];
  const float* bv    = (const float*)d_in[6];
  const float* gamma = (const float*)d_in[7];
  float* out = (float*)d_out;

  short* Qp = (short*)d_ws;                 // [N][8]  bf16  (256 KB)
  short* Kp = Qp + (size_t)NTOK * 8;        // [N][8]  bf16  (256 KB), sigma rows
  short* Vp = Kp + (size_t)NTOK * 8;        // [64][N] bf16  (2 MB), plain V^T
  float* part  = (float*)(Vp + (size_t)64 * NTOK);       // [s][q][64c]

  const size_t base_bytes = (size_t)NTOK * 8 * 2 * 2 + (size_t)64 * NTOK * 2;
  auto fits = [&](int sp) {
    return base_bytes + (size_t)sp * NTOK * 64 * 4 + (size_t)sp * NTOK * 4 <= ws_size;
  };

  // splits=8: 4096 waves = exactly 4/SIMD; grid (8,128) puts split s on XCD s.
  int splits = 8;
  while (splits > 2 && !fits(splits)) splits >>= 1;

  float* lsums = part + (size_t)splits * NTOK * 64;

  proj_qk_kernel<<<NTOK / 256, 256, 0, stream>>>(x, Wq, bq, Wk, bk, Qp, Kp);
  proj_v_kernel<<<NTOK / 256, 256, 0, stream>>>(x, Wv, bv, Vp);
  attn_split_kernel<<<dim3(splits, 128), 256, 0, stream>>>(Qp, Kp, Vp, part, lsums, splits);
  reduce_kernel<<<NTOK / 64, 256, 0, stream>>>(part, lsums, x, gamma, out, splits);
}

// Round 10
// 86.867 us; speedup vs baseline: 2.0112x; 2.0112x over previous
//
#include <hip/hip_runtime.h>
#include <stdint.h>

#define NTOK 16384
#define KVB 64

typedef __attribute__((ext_vector_type(8))) short short8;
typedef __attribute__((ext_vector_type(4))) float f32x4;
typedef __attribute__((ext_vector_type(16))) float f32x16;

// round-to-nearest-even f32 -> bf16 (bit pattern as short)
__device__ __forceinline__ short f2bf_rne(float f) {
  union { float f; unsigned u; } a; a.f = f;
  unsigned r = a.u + 0x7fffu + ((a.u >> 16) & 1u);
  return (short)(r >> 16);
}

// compiler-managed v_exp_f32 (raw asm bypasses the trans-op hazard recognizer)
__device__ __forceinline__ float fast_exp2(float x) {
#if __has_builtin(__builtin_amdgcn_exp2f)
  return __builtin_amdgcn_exp2f(x);
#else
  return exp2f(x);
#endif
}

__device__ __forceinline__ unsigned cvt_pk_bf16(float lo, float hi) {
  unsigned r;
  asm("v_cvt_pk_bf16_f32 %0, %1, %2" : "=v"(r) : "v"(lo), "v"(hi));
  return r;
}

// sigma: involution on 0..31 swapping [4-7]<->[8-11] and [20-23]<->[24-27].
// Storing K row k at slot sigma(k) makes the 32x32 QK^T output's C-rows land
// so that exp'd P packs sequentially into the PV A-fragment (no cross-lane).
__device__ __forceinline__ int sigma32(int s) {
  int t = (s >> 2) & 3;
  return (t == 1 || t == 2) ? (s ^ 12) : s;
}

// ---------------- projection: Q and K in one pass ([N][8] bf16 rows) ----
// K pre-scaled by 1/ln2 (v_exp_f32 = 2^x) and stored sigma-permuted.
__global__ __launch_bounds__(256) void proj_qk_kernel(
    const float* __restrict__ x,
    const float* __restrict__ Wq, const float* __restrict__ bq,
    const float* __restrict__ Wk, const float* __restrict__ bk,
    short* __restrict__ Qp, short* __restrict__ Kp)
{
  __shared__ float sWq[512], sWk[512], sbq[8], sbk[8];
  const int tid = threadIdx.x;
  for (int i = tid; i < 512; i += 256) { sWq[i] = Wq[i]; sWk[i] = Wk[i]; }
  if (tid < 8) { sbq[tid] = bq[tid]; sbk[tid] = bk[tid]; }
  __syncthreads();

  const int n = blockIdx.x * 256 + tid;
  float xv[64];
#pragma unroll
  for (int c = 0; c < 64; ++c) xv[c] = x[c * NTOK + n];

  short8 qv, kv;
#pragma unroll
  for (int d = 0; d < 8; ++d) {
    float qa = sbq[d], ka = sbk[d];
#pragma unroll
    for (int c = 0; c < 64; c += 4) {
      f32x4 wq = *reinterpret_cast<const f32x4*>(&sWq[d * 64 + c]);
      f32x4 wk = *reinterpret_cast<const f32x4*>(&sWk[d * 64 + c]);
      qa += wq[0]*xv[c] + wq[1]*xv[c+1] + wq[2]*xv[c+2] + wq[3]*xv[c+3];
      ka += wk[0]*xv[c] + wk[1]*xv[c+1] + wk[2]*xv[c+2] + wk[3]*xv[c+3];
    }
    qv[d] = f2bf_rne(qa);
    kv[d] = f2bf_rne(ka * 1.44269504f);
  }
  *reinterpret_cast<short8*>(Qp + (size_t)n * 8) = qv;
  const int slot = (n & ~31) | sigma32(n & 31);
  *reinterpret_cast<short8*>(Kp + (size_t)slot * 8) = kv;
}

// ---------------- projection: V in fragment-major layout ----------------
// VF[frag][lane][e], frag=(n>>4)*2+(c>>5), lane=((n>>3)&1)*32+(c&31), e=n&7
// == the exact 32x32x16 B-operand register image, so the attention kernel
// loads each V fragment as ONE contiguous 1KB coalesced read.
// Block: 32 tokens; thread (c = tid&63, oct = tid>>6) computes 8 tokens x 1
// channel from LDS-staged x/W and writes a single contiguous short8.
__global__ __launch_bounds__(256) void proj_v_kernel(
    const float* __restrict__ x,
    const float* __restrict__ Wv, const float* __restrict__ bv,
    short* __restrict__ VF)
{
  __shared__ float sW[64 * 65];   // +1 pad: kills the 64-way bank conflict
  __shared__ float sx[64][32];
  __shared__ float sb[64];
  const int tid = threadIdx.x;
  const int n0 = blockIdx.x * 32;

  for (int i = tid; i < 4096; i += 256) sW[(i >> 6) * 65 + (i & 63)] = Wv[i];
  if (tid < 64) sb[tid] = bv[tid];
  for (int i = tid; i < 2048; i += 256) {
    const int r = i >> 5, col = i & 31;
    sx[r][col] = x[(size_t)r * NTOK + n0 + col];
  }
  __syncthreads();

  const int c   = tid & 63;
  const int oct = tid >> 6;

  float v[8];
  const float bias = sb[c];
#pragma unroll
  for (int j = 0; j < 8; ++j) v[j] = bias;

  for (int cp = 0; cp < 64; ++cp) {
    const float wv = sW[c * 65 + cp];          // 2-way bank alias: free
    const float* xr = &sx[cp][oct * 8];        // wave-uniform: broadcast
#pragma unroll
    for (int j = 0; j < 8; ++j) v[j] += wv * xr[j];
  }

  const int n    = n0 + oct * 8;
  const int frag = (n >> 4) * 2 + (c >> 5);
  const int lane = ((n >> 3) & 1) * 32 + (c & 31);
  short8 ov;
#pragma unroll
  for (int j = 0; j < 8; ++j) ov[j] = f2bf_rne(v[j]);
  *reinterpret_cast<short8*>(VF + (size_t)frag * 512 + lane * 8) = ov;
}

// ---------------- fused attention: 32x32x16, split-K, coalesced V -------
// Wave owns 32 q-rows. Swapped QK^T (A=K sigma-permuted, B=Q zero-padded
// d8->16); exp'd P packs sequentially into PV A-frags. V fragments load as
// contiguous 1KB reads from the fragment-major VF (R9's per-lane-row V reads
// were ~32 scattered cache lines per instr = ~55us of L1 serialization).
// Next-tile K is register-prefetched. lsum is per-lane adds + 1 shfl_xor.
__global__ __launch_bounds__(256, 4) void attn_split_kernel(
    const short* __restrict__ Qp, const short* __restrict__ Kp,
    const short* __restrict__ VF,
    float* __restrict__ part, float* __restrict__ lsums, int splits)
{
  const int tid  = threadIdx.x;
  const int w    = tid >> 6;
  const int lane = tid & 63;
  const int hi   = lane >> 5;
  const int ln   = lane & 31;
  const int s    = blockIdx.x;
  const int qw   = blockIdx.y * 4 + w;   // 0..511
  const int q0   = qw * 32;

  const short8 zero8 = {0,0,0,0,0,0,0,0};
  f32x16 zf16;
#pragma unroll
  for (int i = 0; i < 16; ++i) zf16[i] = 0.f;

  // Q fragment: B[k=8hi+e][q=ln]; hi half zero (d=8 padded to K=16)
  short8 qf = hi ? zero8
                 : *reinterpret_cast<const short8*>(Qp + (size_t)(q0 + ln) * 8);

  f32x16 acc0 = zf16, acc1 = zf16;   // c 0-31 / c 32-63
  float lsum = 0.f;

  const int kvlen = NTOK / splits;
  const int kv_lo = s * kvlen;

  const short* kp  = Kp + ((size_t)kv_lo + ln) * 8;
  const short* vfp = VF + (size_t)kv_lo * 64 + lane * 8;  // tile frag base

  short8 kc0 = *reinterpret_cast<const short8*>(kp);
  short8 kc1 = *reinterpret_cast<const short8*>(kp + 256);

  for (int it = 0; it < kvlen; it += KVB) {
    // 8 V fragments for this tile: contiguous 1KB loads
    short8 vf[8];
#pragma unroll
    for (int j = 0; j < 8; ++j)
      vf[j] = *reinterpret_cast<const short8*>(vfp + j * 512);

    // prefetch next tile's K (reads past slice end land in VF: valid mem)
    kp += KVB * 8;
    short8 kn0 = *reinterpret_cast<const short8*>(kp);
    short8 kn1 = *reinterpret_cast<const short8*>(kp + 256);

    f32x16 sv0 = __builtin_amdgcn_mfma_f32_32x32x16_bf16(kc0, qf, zf16, 0, 0, 0);
    f32x16 sv1 = __builtin_amdgcn_mfma_f32_32x32x16_bf16(kc1, qf, zf16, 0, 0, 0);

#pragma unroll
    for (int b = 0; b < 2; ++b) {
      const f32x16& sv = b ? sv1 : sv0;
      float e[16];
#pragma unroll
      for (int r = 0; r < 16; ++r) e[r] = fast_exp2(sv[r]);
#pragma unroll
      for (int r = 0; r < 16; ++r) lsum += e[r];

      union { short8 s8; unsigned u32[4]; } pa0, pa1;
      pa0.u32[0] = cvt_pk_bf16(e[0],  e[1]);
      pa0.u32[1] = cvt_pk_bf16(e[2],  e[3]);
      pa0.u32[2] = cvt_pk_bf16(e[4],  e[5]);
      pa0.u32[3] = cvt_pk_bf16(e[6],  e[7]);
      pa1.u32[0] = cvt_pk_bf16(e[8],  e[9]);
      pa1.u32[1] = cvt_pk_bf16(e[10], e[11]);
      pa1.u32[2] = cvt_pk_bf16(e[12], e[13]);
      pa1.u32[3] = cvt_pk_bf16(e[14], e[15]);

      acc0 = __builtin_amdgcn_mfma_f32_32x32x16_bf16(pa0.s8, vf[4*b+0], acc0, 0, 0, 0);
      acc1 = __builtin_amdgcn_mfma_f32_32x32x16_bf16(pa0.s8, vf[4*b+1], acc1, 0, 0, 0);
      acc0 = __builtin_amdgcn_mfma_f32_32x32x16_bf16(pa1.s8, vf[4*b+2], acc0, 0, 0, 0);
      acc1 = __builtin_amdgcn_mfma_f32_32x32x16_bf16(pa1.s8, vf[4*b+3], acc1, 0, 0, 0);
    }

    kc0 = kn0; kc1 = kn1;
    vfp += KVB * 64;   // 8 frags * 512 shorts
  }

  // full row denominator for q = ln (hi halves cover disjoint key sets)
  lsum += __shfl_xor(lsum, 32);
  if (lane < 32)
    lsums[(size_t)s * NTOK + q0 + ln] = lsum;

  // partial O, q-major [q][64c]; C layout: row=(r&3)+8*(r>>2)+4*hi, col=ln
  float* pp = part + ((size_t)s * NTOK + q0) * 64;
#pragma unroll
  for (int r = 0; r < 16; ++r) {
    const int qrow = (r & 3) + 8 * (r >> 2) + 4 * hi;
    pp[qrow * 64 + ln]      = acc0[r];
    pp[qrow * 64 + 32 + ln] = acc1[r];
  }
}

// ---------------- reduce: sum partials, normalize, gamma*O + x ----------
__global__ __launch_bounds__(256) void reduce_kernel(
    const float* __restrict__ part, const float* __restrict__ lsums,
    const float* __restrict__ x, const float* __restrict__ gamma,
    float* __restrict__ out, int splits)
{
  __shared__ float tile[64][65];
  __shared__ float linv[64];
  const int tid = threadIdx.x;
  const int qb  = blockIdx.x;

  // phase 1: coalesced q-major reads, sum over splits
  {
    const int qloc = tid >> 2, c0 = (tid & 3) * 16;
    f32x4 a[4] = {{0,0,0,0},{0,0,0,0},{0,0,0,0},{0,0,0,0}};
    float ls = 0.f;
    for (int s = 0; s < splits; ++s) {
      const float* p = part + ((size_t)s * NTOK + qb * 64 + qloc) * 64 + c0;
#pragma unroll
      for (int j = 0; j < 4; ++j)
        a[j] += *reinterpret_cast<const f32x4*>(p + 4 * j);
      if ((tid & 3) == 0)
        ls += lsums[(size_t)s * NTOK + qb * 64 + qloc];
    }
#pragma unroll
    for (int j = 0; j < 4; ++j)
#pragma unroll
      for (int e = 0; e < 4; ++e)
        tile[qloc][c0 + 4 * j + e] = a[j][e];
    if ((tid & 3) == 0) linv[qloc] = 1.f / ls;
  }
  __syncthreads();

  // phase 2: c-major writes (transposed via LDS)
  const int c = tid >> 2, qs = (tid & 3) * 16;
  const float gam = gamma[0];
#pragma unroll
  for (int i = 0; i < 16; ++i) {
    const int q = qs + i;
    const size_t idx = (size_t)c * NTOK + qb * 64 + q;
    out[idx] = gam * tile[q][c] * linv[q] + x[idx];
  }
}

extern "C" void kernel_launch(void* const* d_in, const int* in_sizes, int n_in,
                              void* d_out, int out_size, void* d_ws, size_t ws_size,
                              hipStream_t stream) {
  const float* x     = (const float*)d_in[0];
  const float* Wq    = (const float*)d_in[1];
  const float* bq    = (const float*)d_in[2];
  const float* Wk    = (const float*)d_in[3];
  const float* bk    = (const float*)d_in[4];
  const float* Wv    = (const float*)d_in[5];
  const float* bv    = (const float*)d_in[6];
  const float* gamma = (const float*)d_in[7];
  float* out = (float*)d_out;

  short* Qp = (short*)d_ws;                 // [N][8]  bf16  (256 KB)
  short* Kp = Qp + (size_t)NTOK * 8;        // [N][8]  bf16  (256 KB), sigma rows
  short* VF = Kp + (size_t)NTOK * 8;        // [N/16*2][64][8] bf16 (2 MB) frag-major
  float* part  = (float*)(VF + (size_t)64 * NTOK);       // [s][q][64c]

  const size_t base_bytes = (size_t)NTOK * 8 * 2 * 2 + (size_t)64 * NTOK * 2;
  auto fits = [&](int sp) {
    return base_bytes + (size_t)sp * NTOK * 64 * 4 + (size_t)sp * NTOK * 4 <= ws_size;
  };

  // splits=8: 4096 waves = 4/SIMD; grid (8,128) puts split s on XCD s.
  int splits = 8;
  while (splits > 2 && !fits(splits)) splits >>= 1;

  float* lsums = part + (size_t)splits * NTOK * 64;

  proj_qk_kernel<<<NTOK / 256, 256, 0, stream>>>(x, Wq, bq, Wk, bk, Qp, Kp);
  proj_v_kernel<<<NTOK / 32, 256, 0, stream>>>(x, Wv, bv, VF);
  attn_split_kernel<<<dim3(splits, 128), 256, 0, stream>>>(Qp, Kp, VF, part, lsums, splits);
  reduce_kernel<<<NTOK / 64, 256, 0, stream>>>(part, lsums, x, gamma, out, splits);
}